// Round 4
// baseline (3410.664 us; speedup 1.0000x reference)
//
#include <hip/hip_runtime.h>
#include <hip/hip_bf16.h>
#include <stdint.h>

#define D_DIM 1024
#define P_ROWS 8192
#define K_ROWS 131072
#define M_DIM 512
#define L_STEPS 64
#define BM 128

typedef short bf16x8_t __attribute__((ext_vector_type(8)));
typedef float f32x4_t __attribute__((ext_vector_type(4)));

__device__ __forceinline__ uint32_t f2bf(float f) {
  union { float f; uint32_t u; } c; c.f = f;
  const uint32_t u = c.u;
  return (u + 0x7FFFu + ((u >> 16) & 1u)) >> 16;   // RNE
}

__device__ __forceinline__ bf16x8_t as_bf16x8(uint4 v) {
  union { uint4 u; bf16x8_t h; } c; c.u = v; return c.h;
}

__device__ __forceinline__ bf16x8_t cvt_frag(const float4& a0, const float4& a1) {
  uint32_t p0, p1, p2, p3;
  asm("v_cvt_pk_bf16_f32 %0, %1, %2" : "=v"(p0) : "v"(a0.x), "v"(a0.y));
  asm("v_cvt_pk_bf16_f32 %0, %1, %2" : "=v"(p1) : "v"(a0.z), "v"(a0.w));
  asm("v_cvt_pk_bf16_f32 %0, %1, %2" : "=v"(p2) : "v"(a1.x), "v"(a1.y));
  asm("v_cvt_pk_bf16_f32 %0, %1, %2" : "=v"(p3) : "v"(a1.z), "v"(a1.w));
  union { uint32_t u[4]; bf16x8_t h; } c;
  c.u[0] = p0; c.u[1] = p1; c.u[2] = p2; c.u[3] = p3;
  return c.h;
}

// v[d] += sum_i y[i] * X[i,d]
__global__ void xty_kernel(const float* __restrict__ X, const float* __restrict__ y,
                           float* __restrict__ v) {
  const int d0 = threadIdx.x * 4;
  float a0 = 0.f, a1 = 0.f, a2 = 0.f, a3 = 0.f;
  for (int i = blockIdx.x; i < P_ROWS; i += gridDim.x) {
    const float s = y[i];
    const float4 x = *reinterpret_cast<const float4*>(X + (size_t)i * D_DIM + d0);
    a0 += s * x.x; a1 += s * x.y; a2 += s * x.z; a3 += s * x.w;
  }
  atomicAdd(v + d0 + 0, a0);
  atomicAdd(v + d0 + 1, a1);
  atomicAdd(v + d0 + 2, a2);
  atomicAdd(v + d0 + 3, a3);
}

// wout[d] += sum_i (X[i,:].win) * X[i,d]
__global__ void xtxw_kernel(const float* __restrict__ X, const float* __restrict__ win,
                            float* __restrict__ wout) {
  __shared__ float red[4][D_DIM];
  const int lane = threadIdx.x & 63;
  const int wave = threadIdx.x >> 6;
  const int gw = blockIdx.x * 4 + wave;
  const int nw = gridDim.x * 4;
  float wv[16], acc[16];
#pragma unroll
  for (int q = 0; q < 4; ++q) {
    const float4 tv = *reinterpret_cast<const float4*>(win + q * 256 + lane * 4);
    wv[q*4+0] = tv.x; wv[q*4+1] = tv.y; wv[q*4+2] = tv.z; wv[q*4+3] = tv.w;
  }
#pragma unroll
  for (int j = 0; j < 16; ++j) acc[j] = 0.f;
  for (int i = gw; i < P_ROWS; i += nw) {
    const float* xr = X + (size_t)i * D_DIM;
    float xv[16];
    float dot = 0.f;
#pragma unroll
    for (int q = 0; q < 4; ++q) {
      const float4 tv = *reinterpret_cast<const float4*>(xr + q * 256 + lane * 4);
      xv[q*4+0] = tv.x; xv[q*4+1] = tv.y; xv[q*4+2] = tv.z; xv[q*4+3] = tv.w;
      dot += tv.x * wv[q*4+0] + tv.y * wv[q*4+1] + tv.z * wv[q*4+2] + tv.w * wv[q*4+3];
    }
#pragma unroll
    for (int m = 1; m < 64; m <<= 1) dot += __shfl_xor(dot, m);
#pragma unroll
    for (int j = 0; j < 16; ++j) acc[j] += dot * xv[j];
  }
#pragma unroll
  for (int q = 0; q < 4; ++q) {
    float4 tv;
    tv.x = acc[q*4+0]; tv.y = acc[q*4+1]; tv.z = acc[q*4+2]; tv.w = acc[q*4+3];
    *reinterpret_cast<float4*>(&red[wave][q * 256 + lane * 4]) = tv;
  }
  __syncthreads();
  const int d0 = threadIdx.x * 4;
#pragma unroll
  for (int j = 0; j < 4; ++j)
    atomicAdd(wout + d0 + j, red[0][d0+j] + red[1][d0+j] + red[2][d0+j] + red[3][d0+j]);
}

// rep = gamma*(64 v - 2016 eps u1/P + 41664 eps^2 u2/P^2); emit rep/(L*P) and rep/||rep||
__global__ void combine_kernel(const float* __restrict__ v, const float* __restrict__ u1,
                               const float* __restrict__ u2, const float* __restrict__ gamma_p,
                               float* __restrict__ rep_lin, float* __restrict__ repn) {
  __shared__ float sred[4];
  const float gamma = *gamma_p;
  const float eps = gamma / (float)L_STEPS;
  const float c1 = 2016.0f * eps / (float)P_ROWS;
  const float c2 = 41664.0f * eps * eps / ((float)P_ROWS * (float)P_ROWS);
  const int d0 = threadIdx.x * 4;
  float r[4];
  float ss = 0.f;
#pragma unroll
  for (int j = 0; j < 4; ++j) {
    const float val = gamma * ((float)L_STEPS * v[d0+j] - c1 * u1[d0+j] + c2 * u2[d0+j]);
    r[j] = val;
    ss += val * val;
  }
#pragma unroll
  for (int m = 1; m < 64; m <<= 1) ss += __shfl_xor(ss, m);
  if ((threadIdx.x & 63) == 0) sred[threadIdx.x >> 6] = ss;
  __syncthreads();
  const float norm = sqrtf(sred[0] + sred[1] + sred[2] + sred[3]);
  const float inv_norm = 1.0f / (norm + 1e-8f);
  const float lin_s = 1.0f / ((float)L_STEPS * (float)P_ROWS);
#pragma unroll
  for (int j = 0; j < 4; ++j) {
    rep_lin[d0+j] = r[j] * lin_s;
    repn[d0+j]    = r[j] * inv_norm;
  }
}

// WnF fragment-major: byte addr (s*32+f)*1024 + l*16 holds bf16 x8 of
// W[f*16+(l&15)][s*32+(l>>4)*8 + 0..7] * repn[...]
__global__ void wn_frag_kernel(const float* __restrict__ W, const float* __restrict__ repn,
                               ushort* __restrict__ WnF) {
  const int gid = blockIdx.x * 256 + threadIdx.x;   // 65536
  const int l = gid & 63;
  const int f = (gid >> 6) & 31;
  const int s = gid >> 11;
  const int m = f * 16 + (l & 15);
  const int d0 = s * 32 + ((l >> 4) << 3);
  const float4 w0 = *reinterpret_cast<const float4*>(W + (size_t)m * D_DIM + d0);
  const float4 w1 = *reinterpret_cast<const float4*>(W + (size_t)m * D_DIM + d0 + 4);
  const float4 r0 = *reinterpret_cast<const float4*>(repn + d0);
  const float4 r1 = *reinterpret_cast<const float4*>(repn + d0 + 4);
  uint4 o;
  o.x = f2bf(w0.x*r0.x) | (f2bf(w0.y*r0.y) << 16);
  o.y = f2bf(w0.z*r0.z) | (f2bf(w0.w*r0.w) << 16);
  o.z = f2bf(w1.x*r1.x) | (f2bf(w1.y*r1.y) << 16);
  o.w = f2bf(w1.z*r1.z) | (f2bf(w1.w*r1.w) << 16);
  *reinterpret_cast<uint4*>(WnF + (size_t)gid * 8) = o;
}

// Fused GEMM, LDS-free register streaming:
// 8 waves (2wm x 4wn), wave tile 64x128, 16x16x32 bf16 MFMA, BK=32, 32 phases.
// B frags direct from fragment-major WnF (L2-resident), A frags direct from Xs.
// No LDS staging, no waitcnt-coupled barriers; raw s_barrier per phase for L1 locality.
#define PHASE(BC, BN, SC, DO_PF) do {                                            \
    bf16x8_t Ac[4];                                                              \
    _Pragma("unroll")                                                            \
    for (int mi = 0; mi < 4; ++mi) Ac[mi] = cvt_frag(Af0[mi], Af1[mi]);          \
    if (wn == 0) {                                                               \
      _Pragma("unroll")                                                          \
      for (int mi = 0; mi < 4; ++mi)                                             \
        lin[mi] += Af0[mi].x*r0.x + Af0[mi].y*r0.y + Af0[mi].z*r0.z + Af0[mi].w*r0.w \
                 + Af1[mi].x*r1.x + Af1[mi].y*r1.y + Af1[mi].z*r1.z + Af1[mi].w*r1.w; \
    }                                                                            \
    if (DO_PF) {                                                                 \
      _Pragma("unroll")                                                          \
      for (int ni = 0; ni < 8; ++ni)                                             \
        BN[ni] = *reinterpret_cast<const uint4*>(gB + (size_t)((SC) + 1) * 32768 + ni * 1024); \
      _Pragma("unroll")                                                          \
      for (int mi = 0; mi < 4; ++mi) {                                           \
        Af0[mi] = *reinterpret_cast<const float4*>(gA + (size_t)((SC) + 1) * 128 + mi * 65536); \
        Af1[mi] = *reinterpret_cast<const float4*>(gA + (size_t)((SC) + 1) * 128 + mi * 65536 + 16); \
      }                                                                          \
      if (wn == 0) {                                                             \
        r0 = *reinterpret_cast<const float4*>(gR + (size_t)((SC) + 1) * 128);      \
        r1 = *reinterpret_cast<const float4*>(gR + (size_t)((SC) + 1) * 128 + 16); \
      }                                                                          \
    }                                                                            \
    __builtin_amdgcn_sched_barrier(0);                                           \
    _Pragma("unroll")                                                            \
    for (int mi = 0; mi < 4; ++mi)                                               \
      _Pragma("unroll")                                                          \
      for (int ni = 0; ni < 8; ++ni)                                             \
        acc[mi][ni] = __builtin_amdgcn_mfma_f32_16x16x32_bf16(Ac[mi], as_bf16x8(BC[ni]), acc[mi][ni], 0, 0, 0); \
    __builtin_amdgcn_s_barrier();                                                \
  } while (0)

__global__ __launch_bounds__(512, 4)
void fused_kernel(const float* __restrict__ Xs, const ushort* __restrict__ WnF,
                  const float* __restrict__ rep_lin, const float* __restrict__ b1,
                  const float* __restrict__ aw, const float* __restrict__ b2p,
                  float* __restrict__ out) {
  __shared__ float mlp_acc[BM];
  __shared__ float lin_acc[BM];

  const int t = threadIdx.x;
  const int lane = t & 63;
  const int wid = t >> 6;
  const int wm = wid >> 2;     // 0..1
  const int wn = wid & 3;      // 0..3
  const int fr = lane & 15;
  const int kg = lane >> 4;
  const size_t blockRow = (size_t)blockIdx.x * BM;

  const char* gB = (const char*)WnF + (size_t)wn * 8192 + (size_t)lane * 16;
  const char* gA = (const char*)Xs + (blockRow + (size_t)(wm * 64 + fr)) * 4096 + (size_t)kg * 32;
  const char* gR = (const char*)rep_lin + (size_t)kg * 32;

  if (t < BM) mlp_acc[t] = 0.f;
  __syncthreads();

  uint4 B0[8], B1[8];
  float4 Af0[4], Af1[4], r0, r1;
  float lin[4] = {0.f, 0.f, 0.f, 0.f};
  f32x4_t acc[4][8];
#pragma unroll
  for (int mi = 0; mi < 4; ++mi)
#pragma unroll
    for (int ni = 0; ni < 8; ++ni)
      acc[mi][ni] = f32x4_t{0.f, 0.f, 0.f, 0.f};

  // prologue: load step 0
#pragma unroll
  for (int ni = 0; ni < 8; ++ni)
    B0[ni] = *reinterpret_cast<const uint4*>(gB + ni * 1024);
#pragma unroll
  for (int mi = 0; mi < 4; ++mi) {
    Af0[mi] = *reinterpret_cast<const float4*>(gA + mi * 65536);
    Af1[mi] = *reinterpret_cast<const float4*>(gA + mi * 65536 + 16);
  }
  if (wn == 0) {
    r0 = *reinterpret_cast<const float4*>(gR);
    r1 = *reinterpret_cast<const float4*>(gR + 16);
  }

  for (int su = 0; su < 15; ++su) {
    PHASE(B0, B1, 2 * su,     1);
    PHASE(B1, B0, 2 * su + 1, 1);
  }
  PHASE(B0, B1, 30, 1);
  PHASE(B1, B0, 31, 0);

  // ---- epilogue ----
  float b1r[8], ar[8];
#pragma unroll
  for (int ni = 0; ni < 8; ++ni) {
    const int c = wn * 128 + ni * 16 + fr;
    b1r[ni] = b1[c];
    ar[ni]  = aw[c];
  }
#pragma unroll
  for (int mi = 0; mi < 4; ++mi) {
#pragma unroll
    for (int r = 0; r < 4; ++r) {
      float sum = 0.f;
#pragma unroll
      for (int ni = 0; ni < 8; ++ni) {
        const float h = acc[mi][ni][r] + b1r[ni];
        sum += fmaxf(h, 0.f) * ar[ni];
      }
      sum += __shfl_xor(sum, 1);
      sum += __shfl_xor(sum, 2);
      sum += __shfl_xor(sum, 4);
      sum += __shfl_xor(sum, 8);
      if (fr == 0) {
        const int row = wm * 64 + mi * 16 + kg * 4 + r;
        atomicAdd(&mlp_acc[row], sum);
      }
    }
  }
  if (wn == 0) {
#pragma unroll
    for (int mi = 0; mi < 4; ++mi) {
      lin[mi] += __shfl_xor(lin[mi], 16);
      lin[mi] += __shfl_xor(lin[mi], 32);
    }
    if (lane < 16) {
#pragma unroll
      for (int mi = 0; mi < 4; ++mi)
        lin_acc[wm * 64 + mi * 16 + lane] = lin[mi];
    }
  }
  __syncthreads();
  if (t < BM)
    out[blockRow + t] = lin_acc[t] + mlp_acc[t] + b2p[0];
}

extern "C" void kernel_launch(void* const* d_in, const int* in_sizes, int n_in,
                              void* d_out, int out_size, void* d_ws, size_t ws_size,
                              hipStream_t stream) {
  const float* X     = (const float*)d_in[0];
  const float* y     = (const float*)d_in[1];
  const float* Xs    = (const float*)d_in[2];
  const float* gamma = (const float*)d_in[3];
  const float* W     = (const float*)d_in[4];
  const float* a     = (const float*)d_in[5];
  const float* b1    = (const float*)d_in[6];
  const float* b2    = (const float*)d_in[7];
  float* out = (float*)d_out;

  char* ws = (char*)d_ws;
  float*  v       = (float*)(ws + 0);
  float*  u1      = (float*)(ws + 4096);
  float*  u2      = (float*)(ws + 8192);
  float*  rep_lin = (float*)(ws + 12288);
  float*  repn    = (float*)(ws + 16384);
  ushort* WnF     = (ushort*)(ws + 20480);

  hipMemsetAsync(ws, 0, 3 * 4096, stream);
  hipLaunchKernelGGL(xty_kernel,     dim3(256), dim3(256), 0, stream, X, y, v);
  hipLaunchKernelGGL(xtxw_kernel,    dim3(256), dim3(256), 0, stream, X, v, u1);
  hipLaunchKernelGGL(xtxw_kernel,    dim3(256), dim3(256), 0, stream, X, u1, u2);
  hipLaunchKernelGGL(combine_kernel, dim3(1),   dim3(256), 0, stream, v, u1, u2, gamma, rep_lin, repn);
  hipLaunchKernelGGL(wn_frag_kernel, dim3(256), dim3(256), 0, stream, W, repn, WnF);
  hipLaunchKernelGGL(fused_kernel,   dim3(K_ROWS / BM), dim3(512), 0, stream,
                     Xs, WnF, rep_lin, b1, a, b2, out);
}

// Round 5
// 556.995 us; speedup vs baseline: 6.1233x; 6.1233x over previous
//
#include <hip/hip_runtime.h>
#include <hip/hip_bf16.h>
#include <stdint.h>

#define D_DIM 1024
#define P_ROWS 8192
#define K_ROWS 131072
#define M_DIM 512
#define L_STEPS 64
#define BM 128

typedef short bf16x8_t __attribute__((ext_vector_type(8)));
typedef float f32x4_t __attribute__((ext_vector_type(4)));

__device__ __forceinline__ uint32_t f2bf(float f) {
  union { float f; uint32_t u; } c; c.f = f;
  const uint32_t u = c.u;
  return (u + 0x7FFFu + ((u >> 16) & 1u)) >> 16;   // RNE
}

__device__ __forceinline__ bf16x8_t as_bf16x8(uint4 v) {
  union { uint4 u; bf16x8_t h; } c; c.u = v; return c.h;
}

__device__ __forceinline__ bf16x8_t cvt_frag(const float4& a0, const float4& a1) {
  uint32_t p0, p1, p2, p3;
  asm("v_cvt_pk_bf16_f32 %0, %1, %2" : "=v"(p0) : "v"(a0.x), "v"(a0.y));
  asm("v_cvt_pk_bf16_f32 %0, %1, %2" : "=v"(p1) : "v"(a0.z), "v"(a0.w));
  asm("v_cvt_pk_bf16_f32 %0, %1, %2" : "=v"(p2) : "v"(a1.x), "v"(a1.y));
  asm("v_cvt_pk_bf16_f32 %0, %1, %2" : "=v"(p3) : "v"(a1.z), "v"(a1.w));
  union { uint32_t u[4]; bf16x8_t h; } c;
  c.u[0] = p0; c.u[1] = p1; c.u[2] = p2; c.u[3] = p3;
  return c.h;
}

// v[d] += sum_i y[i] * X[i,d]
__global__ void xty_kernel(const float* __restrict__ X, const float* __restrict__ y,
                           float* __restrict__ v) {
  const int d0 = threadIdx.x * 4;
  float a0 = 0.f, a1 = 0.f, a2 = 0.f, a3 = 0.f;
  for (int i = blockIdx.x; i < P_ROWS; i += gridDim.x) {
    const float s = y[i];
    const float4 x = *reinterpret_cast<const float4*>(X + (size_t)i * D_DIM + d0);
    a0 += s * x.x; a1 += s * x.y; a2 += s * x.z; a3 += s * x.w;
  }
  atomicAdd(v + d0 + 0, a0);
  atomicAdd(v + d0 + 1, a1);
  atomicAdd(v + d0 + 2, a2);
  atomicAdd(v + d0 + 3, a3);
}

// wout[d] += sum_i (X[i,:].win) * X[i,d]
__global__ void xtxw_kernel(const float* __restrict__ X, const float* __restrict__ win,
                            float* __restrict__ wout) {
  __shared__ float red[4][D_DIM];
  const int lane = threadIdx.x & 63;
  const int wave = threadIdx.x >> 6;
  const int gw = blockIdx.x * 4 + wave;
  const int nw = gridDim.x * 4;
  float wv[16], acc[16];
#pragma unroll
  for (int q = 0; q < 4; ++q) {
    const float4 tv = *reinterpret_cast<const float4*>(win + q * 256 + lane * 4);
    wv[q*4+0] = tv.x; wv[q*4+1] = tv.y; wv[q*4+2] = tv.z; wv[q*4+3] = tv.w;
  }
#pragma unroll
  for (int j = 0; j < 16; ++j) acc[j] = 0.f;
  for (int i = gw; i < P_ROWS; i += nw) {
    const float* xr = X + (size_t)i * D_DIM;
    float xv[16];
    float dot = 0.f;
#pragma unroll
    for (int q = 0; q < 4; ++q) {
      const float4 tv = *reinterpret_cast<const float4*>(xr + q * 256 + lane * 4);
      xv[q*4+0] = tv.x; xv[q*4+1] = tv.y; xv[q*4+2] = tv.z; xv[q*4+3] = tv.w;
      dot += tv.x * wv[q*4+0] + tv.y * wv[q*4+1] + tv.z * wv[q*4+2] + tv.w * wv[q*4+3];
    }
#pragma unroll
    for (int m = 1; m < 64; m <<= 1) dot += __shfl_xor(dot, m);
#pragma unroll
    for (int j = 0; j < 16; ++j) acc[j] += dot * xv[j];
  }
#pragma unroll
  for (int q = 0; q < 4; ++q) {
    float4 tv;
    tv.x = acc[q*4+0]; tv.y = acc[q*4+1]; tv.z = acc[q*4+2]; tv.w = acc[q*4+3];
    *reinterpret_cast<float4*>(&red[wave][q * 256 + lane * 4]) = tv;
  }
  __syncthreads();
  const int d0 = threadIdx.x * 4;
#pragma unroll
  for (int j = 0; j < 4; ++j)
    atomicAdd(wout + d0 + j, red[0][d0+j] + red[1][d0+j] + red[2][d0+j] + red[3][d0+j]);
}

// rep = gamma*(64 v - 2016 eps u1/P + 41664 eps^2 u2/P^2); emit rep/(L*P) and rep/||rep||
__global__ void combine_kernel(const float* __restrict__ v, const float* __restrict__ u1,
                               const float* __restrict__ u2, const float* __restrict__ gamma_p,
                               float* __restrict__ rep_lin, float* __restrict__ repn) {
  __shared__ float sred[4];
  const float gamma = *gamma_p;
  const float eps = gamma / (float)L_STEPS;
  const float c1 = 2016.0f * eps / (float)P_ROWS;
  const float c2 = 41664.0f * eps * eps / ((float)P_ROWS * (float)P_ROWS);
  const int d0 = threadIdx.x * 4;
  float r[4];
  float ss = 0.f;
#pragma unroll
  for (int j = 0; j < 4; ++j) {
    const float val = gamma * ((float)L_STEPS * v[d0+j] - c1 * u1[d0+j] + c2 * u2[d0+j]);
    r[j] = val;
    ss += val * val;
  }
#pragma unroll
  for (int m = 1; m < 64; m <<= 1) ss += __shfl_xor(ss, m);
  if ((threadIdx.x & 63) == 0) sred[threadIdx.x >> 6] = ss;
  __syncthreads();
  const float norm = sqrtf(sred[0] + sred[1] + sred[2] + sred[3]);
  const float inv_norm = 1.0f / (norm + 1e-8f);
  const float lin_s = 1.0f / ((float)L_STEPS * (float)P_ROWS);
#pragma unroll
  for (int j = 0; j < 4; ++j) {
    rep_lin[d0+j] = r[j] * lin_s;
    repn[d0+j]    = r[j] * inv_norm;
  }
}

// WnF fragment-major: byte addr (s*32+f)*1024 + l*16 holds bf16 x8 of
// W[f*16+(l&15)][s*32+(l>>4)*8 + 0..7] * repn[...]
__global__ void wn_frag_kernel(const float* __restrict__ W, const float* __restrict__ repn,
                               ushort* __restrict__ WnF) {
  const int gid = blockIdx.x * 256 + threadIdx.x;   // 65536
  const int l = gid & 63;
  const int f = (gid >> 6) & 31;
  const int s = gid >> 11;
  const int m = f * 16 + (l & 15);
  const int d0 = s * 32 + ((l >> 4) << 3);
  const float4 w0 = *reinterpret_cast<const float4*>(W + (size_t)m * D_DIM + d0);
  const float4 w1 = *reinterpret_cast<const float4*>(W + (size_t)m * D_DIM + d0 + 4);
  const float4 r0 = *reinterpret_cast<const float4*>(repn + d0);
  const float4 r1 = *reinterpret_cast<const float4*>(repn + d0 + 4);
  uint4 o;
  o.x = f2bf(w0.x*r0.x) | (f2bf(w0.y*r0.y) << 16);
  o.y = f2bf(w0.z*r0.z) | (f2bf(w0.w*r0.w) << 16);
  o.z = f2bf(w1.x*r1.x) | (f2bf(w1.y*r1.y) << 16);
  o.w = f2bf(w1.z*r1.z) | (f2bf(w1.w*r1.w) << 16);
  *reinterpret_cast<uint4*>(WnF + (size_t)gid * 8) = o;
}

// Fused GEMM, LDS-free register streaming. 8 waves (2wm x 4wn), wave tile 64x128.
// Per phase: issue B(s) (L2-hot, single-buffered) -> cvt A(s) f32->bf16 + lin FMAs
// (hides B latency) -> issue A(s+1)/r(s+1) -> MFMA (compiler waits B only; A stays
// in flight) -> raw s_barrier (keeps waves aligned so L1 merges duplicate A reads).
// No LDS in the dataflow, no manual waitcnt; launch_bounds(512,1) so no reg cap.
#define PHASE(AC0, AC1, RC0, RC1, AN0, AN1, RN0, RN1, SC, DO_PF) do {            \
    uint4 Bv[8];                                                                 \
    _Pragma("unroll")                                                            \
    for (int ni = 0; ni < 8; ++ni)                                               \
      Bv[ni] = *reinterpret_cast<const uint4*>(gB + (size_t)(SC) * 32768 + ni * 1024); \
    bf16x8_t Ac[4];                                                              \
    _Pragma("unroll")                                                            \
    for (int mi = 0; mi < 4; ++mi) {                                             \
      Ac[mi] = cvt_frag(AC0[mi], AC1[mi]);                                       \
      lin[mi] += AC0[mi].x*RC0.x + AC0[mi].y*RC0.y + AC0[mi].z*RC0.z + AC0[mi].w*RC0.w \
               + AC1[mi].x*RC1.x + AC1[mi].y*RC1.y + AC1[mi].z*RC1.z + AC1[mi].w*RC1.w; \
    }                                                                            \
    if (DO_PF) {                                                                 \
      _Pragma("unroll")                                                          \
      for (int mi = 0; mi < 4; ++mi) {                                           \
        AN0[mi] = *reinterpret_cast<const float4*>(gA + (size_t)((SC) + 1) * 128 + mi * 65536); \
        AN1[mi] = *reinterpret_cast<const float4*>(gA + (size_t)((SC) + 1) * 128 + mi * 65536 + 16); \
      }                                                                          \
      RN0 = *reinterpret_cast<const float4*>(gR + (size_t)((SC) + 1) * 128);     \
      RN1 = *reinterpret_cast<const float4*>(gR + (size_t)((SC) + 1) * 128 + 16);\
    }                                                                            \
    __builtin_amdgcn_sched_barrier(0);                                           \
    _Pragma("unroll")                                                            \
    for (int mi = 0; mi < 4; ++mi)                                               \
      _Pragma("unroll")                                                          \
      for (int ni = 0; ni < 8; ++ni)                                             \
        acc[mi][ni] = __builtin_amdgcn_mfma_f32_16x16x32_bf16(Ac[mi], as_bf16x8(Bv[ni]), acc[mi][ni], 0, 0, 0); \
    __builtin_amdgcn_s_barrier();                                                \
  } while (0)

__global__ __launch_bounds__(512, 1)
void fused_kernel(const float* __restrict__ Xs, const ushort* __restrict__ WnF,
                  const float* __restrict__ rep_lin, const float* __restrict__ b1,
                  const float* __restrict__ aw, const float* __restrict__ b2p,
                  float* __restrict__ out) {
  __shared__ float mlp_acc[BM];
  __shared__ float lin_acc[BM];

  const int t = threadIdx.x;
  const int lane = t & 63;
  const int wid = t >> 6;
  const int wm = wid >> 2;     // 0..1
  const int wn = wid & 3;      // 0..3
  const int fr = lane & 15;
  const int kg = lane >> 4;
  const size_t blockRow = (size_t)blockIdx.x * BM;

  const char* gB = (const char*)WnF + (size_t)wn * 8192 + (size_t)lane * 16;
  const char* gA = (const char*)Xs + (blockRow + (size_t)(wm * 64 + fr)) * 4096 + (size_t)kg * 32;
  const char* gR = (const char*)rep_lin + (size_t)kg * 32;

  if (t < BM) mlp_acc[t] = 0.f;
  __syncthreads();

  float4 Aa0[4], Aa1[4], Ab0[4], Ab1[4];
  float4 Ra0, Ra1, Rb0, Rb1;
  float lin[4] = {0.f, 0.f, 0.f, 0.f};
  f32x4_t acc[4][8];
#pragma unroll
  for (int mi = 0; mi < 4; ++mi)
#pragma unroll
    for (int ni = 0; ni < 8; ++ni)
      acc[mi][ni] = f32x4_t{0.f, 0.f, 0.f, 0.f};

  // prologue: A(0), r(0) into set a
#pragma unroll
  for (int mi = 0; mi < 4; ++mi) {
    Aa0[mi] = *reinterpret_cast<const float4*>(gA + mi * 65536);
    Aa1[mi] = *reinterpret_cast<const float4*>(gA + mi * 65536 + 16);
  }
  Ra0 = *reinterpret_cast<const float4*>(gR);
  Ra1 = *reinterpret_cast<const float4*>(gR + 16);

  for (int su = 0; su < 15; ++su) {
    PHASE(Aa0, Aa1, Ra0, Ra1, Ab0, Ab1, Rb0, Rb1, 2 * su,     1);
    PHASE(Ab0, Ab1, Rb0, Rb1, Aa0, Aa1, Ra0, Ra1, 2 * su + 1, 1);
  }
  PHASE(Aa0, Aa1, Ra0, Ra1, Ab0, Ab1, Rb0, Rb1, 30, 1);
  PHASE(Ab0, Ab1, Rb0, Rb1, Aa0, Aa1, Ra0, Ra1, 31, 0);

  // ---- epilogue ----
  float b1r[8], ar[8];
#pragma unroll
  for (int ni = 0; ni < 8; ++ni) {
    const int c = wn * 128 + ni * 16 + fr;
    b1r[ni] = b1[c];
    ar[ni]  = aw[c];
  }
#pragma unroll
  for (int mi = 0; mi < 4; ++mi) {
#pragma unroll
    for (int r = 0; r < 4; ++r) {
      float sum = 0.f;
#pragma unroll
      for (int ni = 0; ni < 8; ++ni) {
        const float h = acc[mi][ni][r] + b1r[ni];
        sum += fmaxf(h, 0.f) * ar[ni];
      }
      sum += __shfl_xor(sum, 1);
      sum += __shfl_xor(sum, 2);
      sum += __shfl_xor(sum, 4);
      sum += __shfl_xor(sum, 8);
      if (fr == 0) {
        const int row = wm * 64 + mi * 16 + kg * 4 + r;
        atomicAdd(&mlp_acc[row], sum);
      }
    }
  }
  if (wn == 0) {
#pragma unroll
    for (int mi = 0; mi < 4; ++mi) {
      lin[mi] += __shfl_xor(lin[mi], 16);
      lin[mi] += __shfl_xor(lin[mi], 32);
    }
    if (lane < 16) {
#pragma unroll
      for (int mi = 0; mi < 4; ++mi)
        lin_acc[wm * 64 + mi * 16 + lane] = lin[mi];
    }
  }
  __syncthreads();
  if (t < BM)
    out[blockRow + t] = lin_acc[t] + mlp_acc[t] + b2p[0];
}

extern "C" void kernel_launch(void* const* d_in, const int* in_sizes, int n_in,
                              void* d_out, int out_size, void* d_ws, size_t ws_size,
                              hipStream_t stream) {
  const float* X     = (const float*)d_in[0];
  const float* y     = (const float*)d_in[1];
  const float* Xs    = (const float*)d_in[2];
  const float* gamma = (const float*)d_in[3];
  const float* W     = (const float*)d_in[4];
  const float* a     = (const float*)d_in[5];
  const float* b1    = (const float*)d_in[6];
  const float* b2    = (const float*)d_in[7];
  float* out = (float*)d_out;

  char* ws = (char*)d_ws;
  float*  v       = (float*)(ws + 0);
  float*  u1      = (float*)(ws + 4096);
  float*  u2      = (float*)(ws + 8192);
  float*  rep_lin = (float*)(ws + 12288);
  float*  repn    = (float*)(ws + 16384);
  ushort* WnF     = (ushort*)(ws + 20480);

  hipMemsetAsync(ws, 0, 3 * 4096, stream);
  hipLaunchKernelGGL(xty_kernel,     dim3(256), dim3(256), 0, stream, X, y, v);
  hipLaunchKernelGGL(xtxw_kernel,    dim3(256), dim3(256), 0, stream, X, v, u1);
  hipLaunchKernelGGL(xtxw_kernel,    dim3(256), dim3(256), 0, stream, X, u1, u2);
  hipLaunchKernelGGL(combine_kernel, dim3(1),   dim3(256), 0, stream, v, u1, u2, gamma, rep_lin, repn);
  hipLaunchKernelGGL(wn_frag_kernel, dim3(256), dim3(256), 0, stream, W, repn, WnF);
  hipLaunchKernelGGL(fused_kernel,   dim3(K_ROWS / BM), dim3(512), 0, stream,
                     Xs, WnF, rep_lin, b1, a, b2, out);
}

// Round 6
// 359.224 us; speedup vs baseline: 9.4945x; 1.5506x over previous
//
#include <hip/hip_runtime.h>
#include <hip/hip_bf16.h>
#include <stdint.h>

#define D_DIM 1024
#define P_ROWS 8192
#define K_ROWS 131072
#define M_DIM 512
#define L_STEPS 64
#define BM 128
#define XS_ROW_BYTES 4096

typedef short bf16x8_t __attribute__((ext_vector_type(8)));
typedef float f32x4_t __attribute__((ext_vector_type(4)));

typedef const __attribute__((address_space(1))) void* gas_t;
typedef __attribute__((address_space(3))) void* las_t;

__device__ __forceinline__ uint32_t f2bf(float f) {
  union { float f; uint32_t u; } c; c.f = f;
  const uint32_t u = c.u;
  return (u + 0x7FFFu + ((u >> 16) & 1u)) >> 16;   // RNE
}

__device__ __forceinline__ bf16x8_t as_bf16x8(uint4 v) {
  union { uint4 u; bf16x8_t h; } c; c.u = v; return c.h;
}

__device__ __forceinline__ bf16x8_t cvt_frag(const f32x4_t& a0, const f32x4_t& a1) {
  uint32_t p0, p1, p2, p3;
  asm("v_cvt_pk_bf16_f32 %0, %1, %2" : "=v"(p0) : "v"(a0[0]), "v"(a0[1]));
  asm("v_cvt_pk_bf16_f32 %0, %1, %2" : "=v"(p1) : "v"(a0[2]), "v"(a0[3]));
  asm("v_cvt_pk_bf16_f32 %0, %1, %2" : "=v"(p2) : "v"(a1[0]), "v"(a1[1]));
  asm("v_cvt_pk_bf16_f32 %0, %1, %2" : "=v"(p3) : "v"(a1[2]), "v"(a1[3]));
  union { uint32_t u[4]; bf16x8_t h; } c;
  c.u[0] = p0; c.u[1] = p1; c.u[2] = p2; c.u[3] = p3;
  return c.h;
}

// v[d] += sum_i y[i] * X[i,d]
__global__ void xty_kernel(const float* __restrict__ X, const float* __restrict__ y,
                           float* __restrict__ v) {
  const int d0 = threadIdx.x * 4;
  float a0 = 0.f, a1 = 0.f, a2 = 0.f, a3 = 0.f;
  for (int i = blockIdx.x; i < P_ROWS; i += gridDim.x) {
    const float s = y[i];
    const float4 x = *reinterpret_cast<const float4*>(X + (size_t)i * D_DIM + d0);
    a0 += s * x.x; a1 += s * x.y; a2 += s * x.z; a3 += s * x.w;
  }
  atomicAdd(v + d0 + 0, a0);
  atomicAdd(v + d0 + 1, a1);
  atomicAdd(v + d0 + 2, a2);
  atomicAdd(v + d0 + 3, a3);
}

// wout[d] += sum_i (X[i,:].win) * X[i,d]
__global__ void xtxw_kernel(const float* __restrict__ X, const float* __restrict__ win,
                            float* __restrict__ wout) {
  __shared__ float red[4][D_DIM];
  const int lane = threadIdx.x & 63;
  const int wave = threadIdx.x >> 6;
  const int gw = blockIdx.x * 4 + wave;
  const int nw = gridDim.x * 4;
  float wv[16], acc[16];
#pragma unroll
  for (int q = 0; q < 4; ++q) {
    const float4 tv = *reinterpret_cast<const float4*>(win + q * 256 + lane * 4);
    wv[q*4+0] = tv.x; wv[q*4+1] = tv.y; wv[q*4+2] = tv.z; wv[q*4+3] = tv.w;
  }
#pragma unroll
  for (int j = 0; j < 16; ++j) acc[j] = 0.f;
  for (int i = gw; i < P_ROWS; i += nw) {
    const float* xr = X + (size_t)i * D_DIM;
    float xv[16];
    float dot = 0.f;
#pragma unroll
    for (int q = 0; q < 4; ++q) {
      const float4 tv = *reinterpret_cast<const float4*>(xr + q * 256 + lane * 4);
      xv[q*4+0] = tv.x; xv[q*4+1] = tv.y; xv[q*4+2] = tv.z; xv[q*4+3] = tv.w;
      dot += tv.x * wv[q*4+0] + tv.y * wv[q*4+1] + tv.z * wv[q*4+2] + tv.w * wv[q*4+3];
    }
#pragma unroll
    for (int m = 1; m < 64; m <<= 1) dot += __shfl_xor(dot, m);
#pragma unroll
    for (int j = 0; j < 16; ++j) acc[j] += dot * xv[j];
  }
#pragma unroll
  for (int q = 0; q < 4; ++q) {
    float4 tv;
    tv.x = acc[q*4+0]; tv.y = acc[q*4+1]; tv.z = acc[q*4+2]; tv.w = acc[q*4+3];
    *reinterpret_cast<float4*>(&red[wave][q * 256 + lane * 4]) = tv;
  }
  __syncthreads();
  const int d0 = threadIdx.x * 4;
#pragma unroll
  for (int j = 0; j < 4; ++j)
    atomicAdd(wout + d0 + j, red[0][d0+j] + red[1][d0+j] + red[2][d0+j] + red[3][d0+j]);
}

// rep = gamma*(64 v - 2016 eps u1/P + 41664 eps^2 u2/P^2); emit rep/(L*P) and rep/||rep||
__global__ void combine_kernel(const float* __restrict__ v, const float* __restrict__ u1,
                               const float* __restrict__ u2, const float* __restrict__ gamma_p,
                               float* __restrict__ rep_lin, float* __restrict__ repn) {
  __shared__ float sred[4];
  const float gamma = *gamma_p;
  const float eps = gamma / (float)L_STEPS;
  const float c1 = 2016.0f * eps / (float)P_ROWS;
  const float c2 = 41664.0f * eps * eps / ((float)P_ROWS * (float)P_ROWS);
  const int d0 = threadIdx.x * 4;
  float r[4];
  float ss = 0.f;
#pragma unroll
  for (int j = 0; j < 4; ++j) {
    const float val = gamma * ((float)L_STEPS * v[d0+j] - c1 * u1[d0+j] + c2 * u2[d0+j]);
    r[j] = val;
    ss += val * val;
  }
#pragma unroll
  for (int m = 1; m < 64; m <<= 1) ss += __shfl_xor(ss, m);
  if ((threadIdx.x & 63) == 0) sred[threadIdx.x >> 6] = ss;
  __syncthreads();
  const float norm = sqrtf(sred[0] + sred[1] + sred[2] + sred[3]);
  const float inv_norm = 1.0f / (norm + 1e-8f);
  const float lin_s = 1.0f / ((float)L_STEPS * (float)P_ROWS);
#pragma unroll
  for (int j = 0; j < 4; ++j) {
    rep_lin[d0+j] = r[j] * lin_s;
    repn[d0+j]    = r[j] * inv_norm;
  }
}

// WnF fragment-major: byte addr (s*32+f)*1024 + l*16 holds bf16 x8 of
// W[f*16+(l&15)][s*32+(l>>4)*8 + 0..7] * repn[...]
__global__ void wn_frag_kernel(const float* __restrict__ W, const float* __restrict__ repn,
                               ushort* __restrict__ WnF) {
  const int gid = blockIdx.x * 256 + threadIdx.x;   // 65536
  const int l = gid & 63;
  const int f = (gid >> 6) & 31;
  const int s = gid >> 11;
  const int m = f * 16 + (l & 15);
  const int d0 = s * 32 + ((l >> 4) << 3);
  const float4 w0 = *reinterpret_cast<const float4*>(W + (size_t)m * D_DIM + d0);
  const float4 w1 = *reinterpret_cast<const float4*>(W + (size_t)m * D_DIM + d0 + 4);
  const float4 r0 = *reinterpret_cast<const float4*>(repn + d0);
  const float4 r1 = *reinterpret_cast<const float4*>(repn + d0 + 4);
  uint4 o;
  o.x = f2bf(w0.x*r0.x) | (f2bf(w0.y*r0.y) << 16);
  o.y = f2bf(w0.z*r0.z) | (f2bf(w0.w*r0.w) << 16);
  o.z = f2bf(w1.x*r1.x) | (f2bf(w1.y*r1.y) << 16);
  o.w = f2bf(w1.z*r1.z) | (f2bf(w1.w*r1.w) << 16);
  *reinterpret_cast<uint4*>(WnF + (size_t)gid * 8) = o;
}

// Fused GEMM. 8 waves (2wm x 4wn), wave tile 64x128, BK=32, 32 steps.
// A: f32 via global_load_lds, 4 x 16KB buffers, staged 3 ahead, pre-swizzled
//    source + XOR-swizzled b128 reads (conflict-free). Zero VGPR staging cost.
// B: fragment-major bf16 from L2 into regs (single-buffered, issued first).
// vmcnt in-order retirement: waiting for B(s) [vmcnt(2)] implies all older
// A-tile DMAs complete -> raw s_barrier with NO drain; A(s+3) stays in flight.
__global__ __launch_bounds__(512, 2)
void fused_kernel(const float* __restrict__ Xs, const ushort* __restrict__ WnF,
                  const float* __restrict__ rep_lin, const float* __restrict__ b1,
                  const float* __restrict__ aw, const float* __restrict__ b2p,
                  float* __restrict__ out) {
  __shared__ __align__(16) char Abuf[4][16384];    // 64 KB, f32 A tiles (swizzled)
  __shared__ __align__(16) float repl[D_DIM];      // 4 KB
  __shared__ float mlp_acc[BM];
  __shared__ float lin_acc[BM];

  const int t = threadIdx.x;
  const int lane = t & 63;
  const int wid = t >> 6;
  const int wm = wid >> 2;     // 0..1
  const int wn = wid & 3;      // 0..3
  const int fr = lane & 15;
  const int kg = lane >> 4;
  const size_t blockRow = (size_t)blockIdx.x * BM;

  // --- DMA staging: lane-linear LDS dst, pre-swizzled global src ---
  // LDS[row][chunkpos p] holds global chunk p ^ (row&7); row = wid*16+j*8+(lane>>3)
  const int sr0 = wid * 16 + (lane >> 3);
  const int sr1 = sr0 + 8;
  const char* gA0 = (const char*)Xs + (blockRow + (size_t)sr0) * XS_ROW_BYTES
                  + (size_t)(((lane & 7) ^ (sr0 & 7)) * 16);
  const char* gA1 = (const char*)Xs + (blockRow + (size_t)sr1) * XS_ROW_BYTES
                  + (size_t)(((lane & 7) ^ (sr1 & 7)) * 16);

  const char* gB = (const char*)WnF + (size_t)wn * 8192 + (size_t)lane * 16;

  // --- swizzled ds_read offsets for A frags ---
  const int fs = fr & 7;
  const int arow = (wm * 64 + fr) * 128;                  // + mi*2048
  const int aoff0 = arow + (((kg * 2)     ^ fs) * 16);
  const int aoff1 = arow + (((kg * 2 + 1) ^ fs) * 16);
  const int roff = kg * 32;                               // + s*128

  auto stage = [&](int tile) {
    char* d0 = &Abuf[0][0] + (size_t)((tile & 3) * 16384 + wid * 2048);
    __builtin_amdgcn_global_load_lds((gas_t)(gA0 + (size_t)tile * 128), (las_t)d0, 16, 0, 0);
    __builtin_amdgcn_global_load_lds((gas_t)(gA1 + (size_t)tile * 128), (las_t)(d0 + 1024), 16, 0, 0);
  };

  f32x4_t acc[4][8];
#pragma unroll
  for (int mi = 0; mi < 4; ++mi)
#pragma unroll
    for (int ni = 0; ni < 8; ++ni)
      acc[mi][ni] = f32x4_t{0.f, 0.f, 0.f, 0.f};
  float lin[4] = {0.f, 0.f, 0.f, 0.f};

  // ---- prologue ----
  if (t < BM) mlp_acc[t] = 0.f;
  repl[t] = rep_lin[t];
  repl[t + 512] = rep_lin[t + 512];
  stage(0); stage(1); stage(2);
  asm volatile("s_waitcnt vmcnt(0)" ::: "memory");
  __syncthreads();

  // ---- main loop ----
  for (int s = 0; s < 32; ++s) {
    const char* Ab = &Abuf[0][0] + (s & 3) * 16384;
    const char* gBs = gB + (size_t)s * 32768;
    // 1) B(s) loads first (L2-hot)
    uint4 Bv[8];
#pragma unroll
    for (int ni = 0; ni < 8; ++ni)
      Bv[ni] = *reinterpret_cast<const uint4*>(gBs + ni * 1024);
    // 2) A-tile DMA 3 ahead
    if (s < 29) stage(s + 3);
    // 3) ds_read current A f32 frags (swizzled, conflict-free)
    f32x4_t va[4], vb[4];
#pragma unroll
    for (int mi = 0; mi < 4; ++mi) {
      va[mi] = *reinterpret_cast<const f32x4_t*>(Ab + aoff0 + mi * 2048);
      vb[mi] = *reinterpret_cast<const f32x4_t*>(Ab + aoff1 + mi * 2048);
    }
    // 4) linear term + cvt to bf16 frags
    if (wn == 0) {
      const f32x4_t rp0 = *reinterpret_cast<const f32x4_t*>((const char*)repl + s * 128 + roff);
      const f32x4_t rp1 = *reinterpret_cast<const f32x4_t*>((const char*)repl + s * 128 + roff + 16);
#pragma unroll
      for (int mi = 0; mi < 4; ++mi)
        lin[mi] += va[mi][0]*rp0[0] + va[mi][1]*rp0[1] + va[mi][2]*rp0[2] + va[mi][3]*rp0[3]
                 + vb[mi][0]*rp1[0] + vb[mi][1]*rp1[1] + vb[mi][2]*rp1[2] + vb[mi][3]*rp1[3];
    }
    bf16x8_t afr[4];
#pragma unroll
    for (int mi = 0; mi < 4; ++mi)
      afr[mi] = cvt_frag(va[mi], vb[mi]);
    // 5) wait B(s) (implies A(s+2) done, in-order); leave A(s+3) in flight
    __builtin_amdgcn_sched_barrier(0);
    if (s < 29) { asm volatile("s_waitcnt vmcnt(2)" ::: "memory"); }
    else        { asm volatile("s_waitcnt vmcnt(0)" ::: "memory"); }
    __builtin_amdgcn_sched_barrier(0);
    // 6) MFMA cluster
    __builtin_amdgcn_s_setprio(1);
#pragma unroll
    for (int mi = 0; mi < 4; ++mi)
#pragma unroll
      for (int ni = 0; ni < 8; ++ni)
        acc[mi][ni] = __builtin_amdgcn_mfma_f32_16x16x32_bf16(afr[mi], as_bf16x8(Bv[ni]), acc[mi][ni], 0, 0, 0);
    __builtin_amdgcn_s_setprio(0);
    __builtin_amdgcn_sched_barrier(0);
    __builtin_amdgcn_s_barrier();
  }

  // ---- epilogue ----
  float b1r[8], ar[8];
#pragma unroll
  for (int ni = 0; ni < 8; ++ni) {
    const int c = wn * 128 + ni * 16 + fr;
    b1r[ni] = b1[c];
    ar[ni]  = aw[c];
  }
#pragma unroll
  for (int mi = 0; mi < 4; ++mi) {
#pragma unroll
    for (int r = 0; r < 4; ++r) {
      float sum = 0.f;
#pragma unroll
      for (int ni = 0; ni < 8; ++ni) {
        const float h = acc[mi][ni][r] + b1r[ni];
        sum += fmaxf(h, 0.f) * ar[ni];
      }
      sum += __shfl_xor(sum, 1);
      sum += __shfl_xor(sum, 2);
      sum += __shfl_xor(sum, 4);
      sum += __shfl_xor(sum, 8);
      if (fr == 0) {
        const int row = wm * 64 + mi * 16 + kg * 4 + r;
        atomicAdd(&mlp_acc[row], sum);
      }
    }
  }
  if (wn == 0) {
#pragma unroll
    for (int mi = 0; mi < 4; ++mi) {
      lin[mi] += __shfl_xor(lin[mi], 16);
      lin[mi] += __shfl_xor(lin[mi], 32);
    }
    if (lane < 16) {
#pragma unroll
      for (int mi = 0; mi < 4; ++mi)
        lin_acc[wm * 64 + mi * 16 + lane] = lin[mi];
    }
  }
  __syncthreads();
  if (t < BM)
    out[blockRow + t] = lin_acc[t] + mlp_acc[t] + b2p[0];
}

extern "C" void kernel_launch(void* const* d_in, const int* in_sizes, int n_in,
                              void* d_out, int out_size, void* d_ws, size_t ws_size,
                              hipStream_t stream) {
  const float* X     = (const float*)d_in[0];
  const float* y     = (const float*)d_in[1];
  const float* Xs    = (const float*)d_in[2];
  const float* gamma = (const float*)d_in[3];
  const float* W     = (const float*)d_in[4];
  const float* a     = (const float*)d_in[5];
  const float* b1    = (const float*)d_in[6];
  const float* b2    = (const float*)d_in[7];
  float* out = (float*)d_out;

  char* ws = (char*)d_ws;
  float*  v       = (float*)(ws + 0);
  float*  u1      = (float*)(ws + 4096);
  float*  u2      = (float*)(ws + 8192);
  float*  rep_lin = (float*)(ws + 12288);
  float*  repn    = (float*)(ws + 16384);
  ushort* WnF     = (ushort*)(ws + 20480);

  hipMemsetAsync(ws, 0, 3 * 4096, stream);
  hipLaunchKernelGGL(xty_kernel,     dim3(256), dim3(256), 0, stream, X, y, v);
  hipLaunchKernelGGL(xtxw_kernel,    dim3(256), dim3(256), 0, stream, X, v, u1);
  hipLaunchKernelGGL(xtxw_kernel,    dim3(256), dim3(256), 0, stream, X, u1, u2);
  hipLaunchKernelGGL(combine_kernel, dim3(1),   dim3(256), 0, stream, v, u1, u2, gamma, rep_lin, repn);
  hipLaunchKernelGGL(wn_frag_kernel, dim3(256), dim3(256), 0, stream, W, repn, WnF);
  hipLaunchKernelGGL(fused_kernel,   dim3(K_ROWS / BM), dim3(512), 0, stream,
                     Xs, WnF, rep_lin, b1, a, b2, out);
}

// Round 7
// 306.456 us; speedup vs baseline: 11.1294x; 1.1722x over previous
//
#include <hip/hip_runtime.h>
#include <hip/hip_bf16.h>
#include <stdint.h>

#define D_DIM 1024
#define P_ROWS 8192
#define K_ROWS 131072
#define M_DIM 512
#define L_STEPS 64
#define BM 64
#define XS_ROW_BYTES 4096

typedef short bf16x8_t __attribute__((ext_vector_type(8)));
typedef float f32x4_t __attribute__((ext_vector_type(4)));

typedef const __attribute__((address_space(1))) void* gas_t;
typedef __attribute__((address_space(3))) void* las_t;

__device__ __forceinline__ uint32_t f2bf(float f) {
  union { float f; uint32_t u; } c; c.f = f;
  const uint32_t u = c.u;
  return (u + 0x7FFFu + ((u >> 16) & 1u)) >> 16;   // RNE
}

__device__ __forceinline__ bf16x8_t as_bf16x8(uint4 v) {
  union { uint4 u; bf16x8_t h; } c; c.u = v; return c.h;
}

__device__ __forceinline__ bf16x8_t cvt_frag(const f32x4_t& a0, const f32x4_t& a1) {
  uint32_t p0, p1, p2, p3;
  asm("v_cvt_pk_bf16_f32 %0, %1, %2" : "=v"(p0) : "v"(a0[0]), "v"(a0[1]));
  asm("v_cvt_pk_bf16_f32 %0, %1, %2" : "=v"(p1) : "v"(a0[2]), "v"(a0[3]));
  asm("v_cvt_pk_bf16_f32 %0, %1, %2" : "=v"(p2) : "v"(a1[0]), "v"(a1[1]));
  asm("v_cvt_pk_bf16_f32 %0, %1, %2" : "=v"(p3) : "v"(a1[2]), "v"(a1[3]));
  union { uint32_t u[4]; bf16x8_t h; } c;
  c.u[0] = p0; c.u[1] = p1; c.u[2] = p2; c.u[3] = p3;
  return c.h;
}

// v[d] += sum_i y[i] * X[i,d]
__global__ void xty_kernel(const float* __restrict__ X, const float* __restrict__ y,
                           float* __restrict__ v) {
  const int d0 = threadIdx.x * 4;
  float a0 = 0.f, a1 = 0.f, a2 = 0.f, a3 = 0.f;
  for (int i = blockIdx.x; i < P_ROWS; i += gridDim.x) {
    const float s = y[i];
    const float4 x = *reinterpret_cast<const float4*>(X + (size_t)i * D_DIM + d0);
    a0 += s * x.x; a1 += s * x.y; a2 += s * x.z; a3 += s * x.w;
  }
  atomicAdd(v + d0 + 0, a0);
  atomicAdd(v + d0 + 1, a1);
  atomicAdd(v + d0 + 2, a2);
  atomicAdd(v + d0 + 3, a3);
}

// wout[d] += sum_i (X[i,:].win) * X[i,d]
__global__ void xtxw_kernel(const float* __restrict__ X, const float* __restrict__ win,
                            float* __restrict__ wout) {
  __shared__ float red[4][D_DIM];
  const int lane = threadIdx.x & 63;
  const int wave = threadIdx.x >> 6;
  const int gw = blockIdx.x * 4 + wave;
  const int nw = gridDim.x * 4;
  float wv[16], acc[16];
#pragma unroll
  for (int q = 0; q < 4; ++q) {
    const float4 tv = *reinterpret_cast<const float4*>(win + q * 256 + lane * 4);
    wv[q*4+0] = tv.x; wv[q*4+1] = tv.y; wv[q*4+2] = tv.z; wv[q*4+3] = tv.w;
  }
#pragma unroll
  for (int j = 0; j < 16; ++j) acc[j] = 0.f;
  for (int i = gw; i < P_ROWS; i += nw) {
    const float* xr = X + (size_t)i * D_DIM;
    float xv[16];
    float dot = 0.f;
#pragma unroll
    for (int q = 0; q < 4; ++q) {
      const float4 tv = *reinterpret_cast<const float4*>(xr + q * 256 + lane * 4);
      xv[q*4+0] = tv.x; xv[q*4+1] = tv.y; xv[q*4+2] = tv.z; xv[q*4+3] = tv.w;
      dot += tv.x * wv[q*4+0] + tv.y * wv[q*4+1] + tv.z * wv[q*4+2] + tv.w * wv[q*4+3];
    }
#pragma unroll
    for (int m = 1; m < 64; m <<= 1) dot += __shfl_xor(dot, m);
#pragma unroll
    for (int j = 0; j < 16; ++j) acc[j] += dot * xv[j];
  }
#pragma unroll
  for (int q = 0; q < 4; ++q) {
    float4 tv;
    tv.x = acc[q*4+0]; tv.y = acc[q*4+1]; tv.z = acc[q*4+2]; tv.w = acc[q*4+3];
    *reinterpret_cast<float4*>(&red[wave][q * 256 + lane * 4]) = tv;
  }
  __syncthreads();
  const int d0 = threadIdx.x * 4;
#pragma unroll
  for (int j = 0; j < 4; ++j)
    atomicAdd(wout + d0 + j, red[0][d0+j] + red[1][d0+j] + red[2][d0+j] + red[3][d0+j]);
}

// rep = gamma*(64 v - 2016 eps u1/P + 41664 eps^2 u2/P^2); emit rep/(L*P) and rep/||rep||
__global__ void combine_kernel(const float* __restrict__ v, const float* __restrict__ u1,
                               const float* __restrict__ u2, const float* __restrict__ gamma_p,
                               float* __restrict__ rep_lin, float* __restrict__ repn) {
  __shared__ float sred[4];
  const float gamma = *gamma_p;
  const float eps = gamma / (float)L_STEPS;
  const float c1 = 2016.0f * eps / (float)P_ROWS;
  const float c2 = 41664.0f * eps * eps / ((float)P_ROWS * (float)P_ROWS);
  const int d0 = threadIdx.x * 4;
  float r[4];
  float ss = 0.f;
#pragma unroll
  for (int j = 0; j < 4; ++j) {
    const float val = gamma * ((float)L_STEPS * v[d0+j] - c1 * u1[d0+j] + c2 * u2[d0+j]);
    r[j] = val;
    ss += val * val;
  }
#pragma unroll
  for (int m = 1; m < 64; m <<= 1) ss += __shfl_xor(ss, m);
  if ((threadIdx.x & 63) == 0) sred[threadIdx.x >> 6] = ss;
  __syncthreads();
  const float norm = sqrtf(sred[0] + sred[1] + sred[2] + sred[3]);
  const float inv_norm = 1.0f / (norm + 1e-8f);
  const float lin_s = 1.0f / ((float)L_STEPS * (float)P_ROWS);
#pragma unroll
  for (int j = 0; j < 4; ++j) {
    rep_lin[d0+j] = r[j] * lin_s;
    repn[d0+j]    = r[j] * inv_norm;
  }
}

// WnF fragment-major: byte addr (s*32+f)*1024 + l*16 holds bf16 x8 of
// W[f*16+(l&15)][s*32+(l>>4)*8 + 0..7] * repn[...]
__global__ void wn_frag_kernel(const float* __restrict__ W, const float* __restrict__ repn,
                               ushort* __restrict__ WnF) {
  const int gid = blockIdx.x * 256 + threadIdx.x;   // 65536
  const int l = gid & 63;
  const int f = (gid >> 6) & 31;
  const int s = gid >> 11;
  const int m = f * 16 + (l & 15);
  const int d0 = s * 32 + ((l >> 4) << 3);
  const float4 w0 = *reinterpret_cast<const float4*>(W + (size_t)m * D_DIM + d0);
  const float4 w1 = *reinterpret_cast<const float4*>(W + (size_t)m * D_DIM + d0 + 4);
  const float4 r0 = *reinterpret_cast<const float4*>(repn + d0);
  const float4 r1 = *reinterpret_cast<const float4*>(repn + d0 + 4);
  uint4 o;
  o.x = f2bf(w0.x*r0.x) | (f2bf(w0.y*r0.y) << 16);
  o.y = f2bf(w0.z*r0.z) | (f2bf(w0.w*r0.w) << 16);
  o.z = f2bf(w1.x*r1.x) | (f2bf(w1.y*r1.y) << 16);
  o.w = f2bf(w1.z*r1.z) | (f2bf(w1.w*r1.w) << 16);
  *reinterpret_cast<uint4*>(WnF + (size_t)gid * 8) = o;
}

// Fused GEMM. BM=64, BN=512(full), 256 threads = 4 waves (one per SIMD, wn=0..3),
// wave tile 64x128, BK=32, 32 steps. ~224 VGPR + 37 KB LDS -> 2 independent
// blocks/CU (the round-7 lever: decouple the per-step serial chain across blocks).
// A: f32 via global_load_lds, 4 x 8KB buffers, depth-3 prefetch, pre-swizzled
//    source + XOR-swizzled b128 reads (conflict-free, zero VGPR cost).
// B: fragment-major bf16 from L2 into regs, issued first, counted vmcnt(2)
//    before MFMA leaves A(s+3) in flight across the raw s_barrier.
__global__ __launch_bounds__(256, 2)
void fused_kernel(const float* __restrict__ Xs, const ushort* __restrict__ WnF,
                  const float* __restrict__ rep_lin, const float* __restrict__ b1,
                  const float* __restrict__ aw, const float* __restrict__ b2p,
                  float* __restrict__ out) {
  __shared__ __align__(16) char Abuf[4][8192];     // 32 KB, f32 A tiles (swizzled)
  __shared__ __align__(16) float repl[D_DIM];      // 4 KB
  __shared__ float mlp_acc[BM];
  __shared__ float lin_acc[BM];

  const int t = threadIdx.x;
  const int lane = t & 63;
  const int wn = t >> 6;       // 0..3 (wave id == N-slice)
  const int fr = lane & 15;
  const int kg = lane >> 4;
  const size_t blockRow = (size_t)blockIdx.x * BM;

  // --- DMA staging: lane-linear LDS dst, pre-swizzled global src ---
  const int sr0 = wn * 16 + (lane >> 3);           // rows 0..63
  const int sr1 = sr0 + 8;
  const char* gA0 = (const char*)Xs + (blockRow + (size_t)sr0) * XS_ROW_BYTES
                  + (size_t)(((lane & 7) ^ (sr0 & 7)) * 16);
  const char* gA1 = (const char*)Xs + (blockRow + (size_t)sr1) * XS_ROW_BYTES
                  + (size_t)(((lane & 7) ^ (sr1 & 7)) * 16);

  const char* gB = (const char*)WnF + (size_t)wn * 8192 + (size_t)lane * 16;

  // --- swizzled ds_read offsets for A frags (row = fr + mi*16) ---
  const int fs = fr & 7;
  const int aoff0 = fr * 128 + (((kg * 2)     ^ fs) * 16);   // + mi*2048
  const int aoff1 = fr * 128 + (((kg * 2 + 1) ^ fs) * 16);
  const int roff = kg * 32;                                  // + s*128

  auto stage = [&](int tile) {
    char* d0 = &Abuf[0][0] + (size_t)((tile & 3) * 8192 + wn * 2048);
    __builtin_amdgcn_global_load_lds((gas_t)(gA0 + (size_t)tile * 128), (las_t)d0, 16, 0, 0);
    __builtin_amdgcn_global_load_lds((gas_t)(gA1 + (size_t)tile * 128), (las_t)(d0 + 1024), 16, 0, 0);
  };

  f32x4_t acc[4][8];
#pragma unroll
  for (int mi = 0; mi < 4; ++mi)
#pragma unroll
    for (int ni = 0; ni < 8; ++ni)
      acc[mi][ni] = f32x4_t{0.f, 0.f, 0.f, 0.f};
  float lin[4] = {0.f, 0.f, 0.f, 0.f};

  // ---- prologue ----
  if (t < BM) mlp_acc[t] = 0.f;
  *reinterpret_cast<float4*>(&repl[t * 4]) = *reinterpret_cast<const float4*>(rep_lin + t * 4);
  stage(0); stage(1); stage(2);
  asm volatile("s_waitcnt vmcnt(0)" ::: "memory");
  __syncthreads();

  // ---- main loop ----
  for (int s = 0; s < 32; ++s) {
    const char* Ab = &Abuf[0][0] + (s & 3) * 8192;
    const char* gBs = gB + (size_t)s * 32768;
    // 1) B(s) loads first (L2-hot)
    uint4 Bv[8];
#pragma unroll
    for (int ni = 0; ni < 8; ++ni)
      Bv[ni] = *reinterpret_cast<const uint4*>(gBs + ni * 1024);
    // 2) A-tile DMA 3 ahead
    if (s < 29) stage(s + 3);
    // 3) ds_read current A f32 frags (swizzled, conflict-free)
    f32x4_t va[4], vb[4];
#pragma unroll
    for (int mi = 0; mi < 4; ++mi) {
      va[mi] = *reinterpret_cast<const f32x4_t*>(Ab + aoff0 + mi * 2048);
      vb[mi] = *reinterpret_cast<const f32x4_t*>(Ab + aoff1 + mi * 2048);
    }
    // 4) linear term + cvt to bf16 frags
    if (wn == 0) {
      const f32x4_t rp0 = *reinterpret_cast<const f32x4_t*>((const char*)repl + s * 128 + roff);
      const f32x4_t rp1 = *reinterpret_cast<const f32x4_t*>((const char*)repl + s * 128 + roff + 16);
#pragma unroll
      for (int mi = 0; mi < 4; ++mi)
        lin[mi] += va[mi][0]*rp0[0] + va[mi][1]*rp0[1] + va[mi][2]*rp0[2] + va[mi][3]*rp0[3]
                 + vb[mi][0]*rp1[0] + vb[mi][1]*rp1[1] + vb[mi][2]*rp1[2] + vb[mi][3]*rp1[3];
    }
    bf16x8_t afr[4];
#pragma unroll
    for (int mi = 0; mi < 4; ++mi)
      afr[mi] = cvt_frag(va[mi], vb[mi]);
    // 5) wait B(s) (in-order => implies A(s+2) done); leave A(s+3) in flight
    __builtin_amdgcn_sched_barrier(0);
    if (s < 29) { asm volatile("s_waitcnt vmcnt(2)" ::: "memory"); }
    else        { asm volatile("s_waitcnt vmcnt(0)" ::: "memory"); }
    __builtin_amdgcn_sched_barrier(0);
    // 6) MFMA cluster
    __builtin_amdgcn_s_setprio(1);
#pragma unroll
    for (int mi = 0; mi < 4; ++mi)
#pragma unroll
      for (int ni = 0; ni < 8; ++ni)
        acc[mi][ni] = __builtin_amdgcn_mfma_f32_16x16x32_bf16(afr[mi], as_bf16x8(Bv[ni]), acc[mi][ni], 0, 0, 0);
    __builtin_amdgcn_s_setprio(0);
    __builtin_amdgcn_sched_barrier(0);
    __builtin_amdgcn_s_barrier();
    __builtin_amdgcn_sched_barrier(0);   // keep next-step loads below the barrier
  }

  // ---- epilogue ----
  float b1r[8], ar[8];
#pragma unroll
  for (int ni = 0; ni < 8; ++ni) {
    const int c = wn * 128 + ni * 16 + fr;
    b1r[ni] = b1[c];
    ar[ni]  = aw[c];
  }
#pragma unroll
  for (int mi = 0; mi < 4; ++mi) {
#pragma unroll
    for (int r = 0; r < 4; ++r) {
      float sum = 0.f;
#pragma unroll
      for (int ni = 0; ni < 8; ++ni) {
        const float h = acc[mi][ni][r] + b1r[ni];
        sum += fmaxf(h, 0.f) * ar[ni];
      }
      sum += __shfl_xor(sum, 1);
      sum += __shfl_xor(sum, 2);
      sum += __shfl_xor(sum, 4);
      sum += __shfl_xor(sum, 8);
      if (fr == 0) {
        const int row = mi * 16 + kg * 4 + r;
        atomicAdd(&mlp_acc[row], sum);
      }
    }
  }
  if (wn == 0) {
#pragma unroll
    for (int mi = 0; mi < 4; ++mi) {
      lin[mi] += __shfl_xor(lin[mi], 16);
      lin[mi] += __shfl_xor(lin[mi], 32);
    }
    if (lane < 16) {
#pragma unroll
      for (int mi = 0; mi < 4; ++mi)
        lin_acc[mi * 16 + lane] = lin[mi];
    }
  }
  __syncthreads();
  if (t < BM)
    out[blockRow + t] = lin_acc[t] + mlp_acc[t] + b2p[0];
}

extern "C" void kernel_launch(void* const* d_in, const int* in_sizes, int n_in,
                              void* d_out, int out_size, void* d_ws, size_t ws_size,
                              hipStream_t stream) {
  const float* X     = (const float*)d_in[0];
  const float* y     = (const float*)d_in[1];
  const float* Xs    = (const float*)d_in[2];
  const float* gamma = (const float*)d_in[3];
  const float* W     = (const float*)d_in[4];
  const float* a     = (const float*)d_in[5];
  const float* b1    = (const float*)d_in[6];
  const float* b2    = (const float*)d_in[7];
  float* out = (float*)d_out;

  char* ws = (char*)d_ws;
  float*  v       = (float*)(ws + 0);
  float*  u1      = (float*)(ws + 4096);
  float*  u2      = (float*)(ws + 8192);
  float*  rep_lin = (float*)(ws + 12288);
  float*  repn    = (float*)(ws + 16384);
  ushort* WnF     = (ushort*)(ws + 20480);

  hipMemsetAsync(ws, 0, 3 * 4096, stream);
  hipLaunchKernelGGL(xty_kernel,     dim3(256), dim3(256), 0, stream, X, y, v);
  hipLaunchKernelGGL(xtxw_kernel,    dim3(256), dim3(256), 0, stream, X, v, u1);
  hipLaunchKernelGGL(xtxw_kernel,    dim3(256), dim3(256), 0, stream, X, u1, u2);
  hipLaunchKernelGGL(combine_kernel, dim3(1),   dim3(256), 0, stream, v, u1, u2, gamma, rep_lin, repn);
  hipLaunchKernelGGL(wn_frag_kernel, dim3(256), dim3(256), 0, stream, W, repn, WnF);
  hipLaunchKernelGGL(fused_kernel,   dim3(K_ROWS / BM), dim3(256), 0, stream,
                     Xs, WnF, rep_lin, b1, a, b2, out);
}